// Round 6
// baseline (311.809 us; speedup 1.0000x reference)
//
#include <hip/hip_runtime.h>
#include <hip/hip_bf16.h>

// Problem constants
#define BB 32
#define CIN 96
#define TT 288
#define VV 25
#define SS 3
#define COUT 96
#define WSZ 5
#define BN_EPS 1e-5f
#define TV (TT*VV)              // 7200
#define ELEMS (BB*COUT*TV)      // 22118400
#define KK 288                  // fused GEMM K = s*96+i
#define XCOLS 64                // XAtile cols allocated (50 used; 64 so junk reads stay in-bounds)

typedef __attribute__((ext_vector_type(8))) short bf16x8;
typedef __attribute__((ext_vector_type(4))) float f32x4;

__device__ __forceinline__ unsigned short f2bf(float f) {
    unsigned u = __float_as_uint(f);
    return (unsigned short)((u + 0x7fffu + ((u >> 16) & 1u)) >> 16);  // RNE
}
__device__ __forceinline__ unsigned pkbf2(float a, float b) {
    __hip_bfloat162 h = __float22bfloat162_rn(make_float2(a, b));  // v_cvt_pk_bf16_f32
    return *(unsigned*)&h;
}

// ---------------------------------------------------------------------------
// prep: Wflat[c][k=s*96+i] = bf16(conv_w[(s*96+c)*96+i]);
//       Bfr[f=s*2+nt][lane][j] = B-fragment of A_s for 16x16x32 MFMA;
//       zbias[c*25+m] = sum_s cb[s*96+c] * sum_n A[s,n,m];  stats = 0.
// ---------------------------------------------------------------------------
__global__ __launch_bounds__(256) void prep(
    const float* __restrict__ conv_w, const float* __restrict__ A,
    const float* __restrict__ cb,
    __hip_bfloat16* __restrict__ Wflat,   // [96][288]
    __hip_bfloat16* __restrict__ Bfr,     // [6][64][8]
    float* __restrict__ zbias,            // [2400]
    float* __restrict__ stats)            // [192]
{
    int id = blockIdx.x*256 + threadIdx.x;
    if (id < 27648) {
        int c = id / KK, k = id - c*KK;
        int s = k / CIN, i = k - s*CIN;
        Wflat[id] = __float2bfloat16(conv_w[(s*COUT + c)*CIN + i]);
    } else if (id < 27648 + 3072) {
        int e = id - 27648;               // f*512 + l*8 + j
        int f = e >> 9, rem = e & 511;
        int l = rem >> 3, j = rem & 7;
        int s = f >> 1, nt = f & 1;
        int n = (l >> 4)*8 + j;
        int m = nt*16 + (l & 15);
        float v = (n < VV && m < VV) ? A[(s*VV + n)*VV + m] : 0.0f;
        Bfr[e] = __float2bfloat16(v);
    } else if (id < 27648 + 3072 + 2400) {
        int e = id - 27648 - 3072;
        int c = e / VV, m = e - c*VV;
        float v = 0.f;
        #pragma unroll
        for (int s = 0; s < SS; ++s) {
            float sa = 0.f;
            #pragma unroll
            for (int n = 0; n < VV; ++n) sa += A[(s*VV + n)*VV + m];
            v = fmaf(cb[s*COUT + c], sa, v);
        }
        zbias[e] = v;
    } else if (id < 27648 + 3072 + 2400 + 192) {
        stats[id - 27648 - 3072 - 2400] = 0.0f;
    }
}

// ---------------------------------------------------------------------------
// fused: per (b, t-tile of 2):
//  prefetch: ALL 27 Wflat A-fragments for phase 2 -> registers (latency
//            hides under phase 1's MFMA work).
//  phase 1: XAt[col=(tl,m)][k=(s,i)] = sum_n x[b,i,t0+tl,n] * A[s,n,m]
//           via MFMA; scatter bf16 pairs to LDS with XOR chunk swizzle.
//  phase 2: z[c][col] = sum_k Wflat[c][k] * XAt[col][k]  (register A-frags,
//           LDS B-frags), + zbias, written directly to out[b][c][t][m].
// ---------------------------------------------------------------------------
__global__ __launch_bounds__(256, 2) void fused(
    const float* __restrict__ x,
    const __hip_bfloat16* __restrict__ Wflat,
    const __hip_bfloat16* __restrict__ Bfr,
    const float* __restrict__ zbias,
    float* __restrict__ out)
{
    __shared__ __hip_bfloat16 XAt[XCOLS*KK];  // 36,864 B
    const int tid  = threadIdx.x;
    const int lane = tid & 63;
    const int wave = tid >> 6;
    const int quad = lane >> 4;       // 0..3
    const int lrow = lane & 15;
    const int tile = blockIdx.x;      // 0..143
    const int b    = blockIdx.y;      // 0..31
    const int t0   = tile*2;
    const int mh = wave & 1, nh = wave >> 1;

    // ---- prefetch phase-2 A-fragments (Wflat) into registers
    bf16x8 wfrag[9][3];
    #pragma unroll
    for (int it = 0; it < 9; ++it)
        #pragma unroll
        for (int mt = 0; mt < 3; ++mt)
            wfrag[it][mt] = *(const bf16x8*)(Wflat
                + ((mh*3 + mt)*16 + lrow)*KK + it*32 + quad*8);

    // 6 B1 fragments (A_s matrices), precomputed per-lane by prep
    bf16x8 bf1[6];
    #pragma unroll
    for (int f = 0; f < 6; ++f)
        bf1[f] = *(const bf16x8*)(Bfr + (f*64 + lane)*8);

    // ---- phase 1: wave w handles M-tiles 3w..3w+2 (rows = i*2+tl)
    #pragma unroll
    for (int mt3 = 0; mt3 < 3; ++mt3) {
        const int Mtile = wave*3 + mt3;
        const int arow = Mtile*16 + lrow;
        const int ai = arow >> 1, atl = arow & 1;
        const float* xrow = x + ((size_t)(b*CIN + ai)*TT + (t0 + atl))*VV;
        float xv[8];
        if (quad < 3) {
            #pragma unroll
            for (int j = 0; j < 8; ++j) xv[j] = xrow[quad*8 + j];
        } else {
            #pragma unroll
            for (int j = 0; j < 8; ++j) xv[j] = 0.f;
            xv[0] = xrow[24];   // n=24 valid; k=25..31 hit zero B entries
        }
        bf16x8 af;
        #pragma unroll
        for (int j = 0; j < 8; j += 2)
            ((unsigned*)&af)[j >> 1] = pkbf2(xv[j], xv[j+1]);

        const int i0 = Mtile*8 + quad*2;
        #pragma unroll
        for (int s = 0; s < SS; ++s) {
            #pragma unroll
            for (int nt = 0; nt < 2; ++nt) {
                f32x4 d = {0.f, 0.f, 0.f, 0.f};
                d = __builtin_amdgcn_mfma_f32_16x16x32_bf16(af, bf1[s*2+nt], d, 0, 0, 0);
                const int m = nt*16 + lrow;
                if (m < VV) {
                    const int k0 = s*CIN + i0;         // even
                    const int g  = k0 >> 3, o = k0 & 7;
                    #pragma unroll
                    for (int tl = 0; tl < 2; ++tl) {   // pair (d[tl], d[tl+2]) -> (i0, i0+1)
                        const int col = tl*VV + m;
                        const int gs  = (g & ~3) | ((g & 3) ^ ((col >> 1) & 3));
                        ((unsigned int*)XAt)[(col*KK + gs*8 + o) >> 1] =
                            pkbf2(d[tl], d[tl+2]);
                    }
                }
            }
        }
    }
    __syncthreads();

    // ---- phase 2: wave split 2x2: mh -> c-tiles, nh -> col-tiles
    f32x4 acc[3][2] = {};
    #pragma unroll
    for (int it = 0; it < 9; ++it) {
        bf16x8 bfrag[2];
        #pragma unroll
        for (int ct = 0; ct < 2; ++ct) {
            const int cl = (nh*2 + ct)*16 + lrow;           // col (junk >=50 ok)
            const int g0 = it*4 + (quad ^ ((cl >> 1) & 3));
            bfrag[ct] = *(const bf16x8*)&XAt[cl*KK + g0*8];
        }
        #pragma unroll
        for (int mt = 0; mt < 3; ++mt)
            #pragma unroll
            for (int ct = 0; ct < 2; ++ct)
                acc[mt][ct] = __builtin_amdgcn_mfma_f32_16x16x32_bf16(
                    wfrag[it][mt], bfrag[ct], acc[mt][ct], 0, 0, 0);
    }

    // ---- epilogue: D col = lane&15, row = quad*4+r ; scatter + zbias
    #pragma unroll
    for (int ct = 0; ct < 2; ++ct) {
        const int cl = (nh*2 + ct)*16 + lrow;
        if (cl < 2*VV) {
            const int tl = (cl >= VV) ? 1 : 0;
            const int m  = cl - tl*VV;
            float* obase = out + ((size_t)b*COUT*TT + (t0 + tl))*VV + m;
            #pragma unroll
            for (int mt = 0; mt < 3; ++mt) {
                const int cbase = (mh*3 + mt)*16 + quad*4;
                #pragma unroll
                for (int r = 0; r < 4; ++r) {
                    const int c = cbase + r;
                    obase[(size_t)c*TV] = acc[mt][ct][r] + zbias[c*VV + m];
                }
            }
        }
    }
}

// ---------------------------------------------------------------------------
// k2: per (b,c) slab: stage raw z in LDS, compute window-5 average, write it
// back IN PLACE (slab-local, race-free), accumulate per-channel sum/sumsq.
// ---------------------------------------------------------------------------
__global__ __launch_bounds__(256) void k2_win_stats(
    float* __restrict__ buf, float* __restrict__ ssum, float* __restrict__ ssq)
{
    __shared__ float zs[TV];    // 28.8 KB
    __shared__ float red[8];
    const int tid = threadIdx.x;
    const int b = blockIdx.x / COUT;
    const int c = blockIdx.x - b*COUT;
    float* slab = buf + (size_t)(b*COUT + c) * TV;
    float4* slab4 = (float4*)slab;
    float4* zs4 = (float4*)zs;
    for (int e = tid; e < TV/4; e += 256) zs4[e] = slab4[e];
    __syncthreads();

    float ls = 0.f, ls2 = 0.f;
    for (int u = tid; u < TV/4; u += 256) {
        float4 o;
        #pragma unroll
        for (int jj = 0; jj < 4; ++jj) {
            int e = u*4 + jj;
            int t = e / VV;
            float acc = zs[e];
            if (t >= 1)    acc += zs[e - VV];
            if (t >= 2)    acc += zs[e - 2*VV];
            if (t <= TT-2) acc += zs[e + VV];
            if (t <= TT-3) acc += zs[e + 2*VV];
            acc *= (1.0f / WSZ);
            ((float*)&o)[jj] = acc;
            ls  += acc;
            ls2 += acc * acc;
        }
        slab4[u] = o;
    }
    #pragma unroll
    for (int off = 32; off > 0; off >>= 1) {
        ls  += __shfl_down(ls,  off, 64);
        ls2 += __shfl_down(ls2, off, 64);
    }
    int lane = tid & 63, wid = tid >> 6;
    if (lane == 0) { red[wid*2] = ls; red[wid*2+1] = ls2; }
    __syncthreads();
    if (tid == 0) {
        atomicAdd(&ssum[c], red[0] + red[2] + red[4] + red[6]);
        atomicAdd(&ssq[c],  red[1] + red[3] + red[5] + red[7]);
    }
}

__global__ void k3_finalize(const float* __restrict__ ssum, const float* __restrict__ ssq,
                            const float* __restrict__ gamma, const float* __restrict__ beta,
                            float* __restrict__ scale, float* __restrict__ bias)
{
    int c = threadIdx.x;
    if (c < COUT) {
        const float invN = 1.0f / (float)(BB * TV);
        float mean = ssum[c] * invN;
        float var  = ssq[c] * invN - mean * mean;
        float inv  = rsqrtf(var + BN_EPS);
        float sc   = gamma[c] * inv;
        scale[c] = sc;
        bias[c]  = beta[c] - mean * sc;
    }
}

// ---------------------------------------------------------------------------
// k4: pure elementwise scale + bias + relu on the windowed values (float4).
// ---------------------------------------------------------------------------
__global__ __launch_bounds__(256) void k4_scale_relu(
    float4* __restrict__ out, const float* __restrict__ scale, const float* __restrict__ bias)
{
    size_t i4 = (size_t)blockIdx.x * 256 + threadIdx.x;   // grid sized exactly
    int c = (int)((i4 * 4 / TV) % COUT);                  // TV%4==0 -> uniform in float4
    float sc = scale[c], bi = bias[c];
    float4 v = out[i4];
    v.x = fmaxf(fmaf(v.x, sc, bi), 0.f);
    v.y = fmaxf(fmaf(v.y, sc, bi), 0.f);
    v.z = fmaxf(fmaf(v.z, sc, bi), 0.f);
    v.w = fmaxf(fmaf(v.w, sc, bi), 0.f);
    out[i4] = v;
}

extern "C" void kernel_launch(void* const* d_in, const int* in_sizes, int n_in,
                              void* d_out, int out_size, void* d_ws, size_t ws_size,
                              hipStream_t stream) {
    const float* x      = (const float*)d_in[0];
    const float* A      = (const float*)d_in[1];
    const float* conv_w = (const float*)d_in[2];
    const float* conv_b = (const float*)d_in[3];
    const float* gamma  = (const float*)d_in[4];
    const float* beta   = (const float*)d_in[5];
    float* out = (float*)d_out;

    // ws layout: zbias(2400 f) | ssum(96) | ssq(96) | scale(96) | bias(96)
    //            | Wflat (27648 bf16) | Bfr (3072 bf16)
    float* zbias = (float*)d_ws;
    float* ssum  = zbias + 2400;
    float* ssq   = ssum + COUT;
    float* scale = ssq  + COUT;
    float* bias  = scale + COUT;
    __hip_bfloat16* Wflat = (__hip_bfloat16*)(bias + COUT);
    __hip_bfloat16* Bfr   = Wflat + (size_t)COUT * KK;

    prep <<<dim3(131),        dim3(256), 0, stream>>>(conv_w, A, conv_b, Wflat, Bfr, zbias, ssum);
    fused<<<dim3(TT/2, BB),   dim3(256), 0, stream>>>(x, Wflat, Bfr, zbias, out);
    k2_win_stats<<<dim3(BB*COUT), dim3(256), 0, stream>>>(out, ssum, ssq);
    k3_finalize<<<dim3(1),    dim3(128), 0, stream>>>(ssum, ssq, gamma, beta, scale, bias);
    k4_scale_relu<<<dim3(ELEMS/4/256), dim3(256), 0, stream>>>((float4*)out, scale, bias);
}